// Round 1
// baseline (524.771 us; speedup 1.0000x reference)
//
#include <hip/hip_runtime.h>
#include <stdint.h>

#define NN 16384
#define FD 128

typedef float f32x4 __attribute__((ext_vector_type(4)));
typedef float f32x16 __attribute__((ext_vector_type(16)));
typedef __bf16 bf16x8 __attribute__((ext_vector_type(8)));
typedef unsigned short u16x8 __attribute__((ext_vector_type(8)));
typedef unsigned short u16x4 __attribute__((ext_vector_type(4)));

static __device__ __forceinline__ unsigned short f2bf(float x) {
  return __builtin_bit_cast(unsigned short, (__bf16)x);
}

static __device__ __forceinline__ u16x8 pack8(f32x4 a, f32x4 b) {
  u16x8 r;
  r[0] = f2bf(a.x); r[1] = f2bf(a.y); r[2] = f2bf(a.z); r[3] = f2bf(a.w);
  r[4] = f2bf(b.x); r[5] = f2bf(b.y); r[6] = f2bf(b.z); r[7] = f2bf(b.w);
  return r;
}

// async global->LDS, 16B per lane; LDS dest = wave-uniform base + lane*16
static __device__ __forceinline__ void gload_lds16(const void* g, void* l) {
  __builtin_amdgcn_global_load_lds(
      (const __attribute__((address_space(1))) unsigned int*)(uintptr_t)g,
      (__attribute__((address_space(3))) unsigned int*)(unsigned int)(uintptr_t)l,
      16, 0, 0);
}

// ---------------- kernel 1: norm[i] = (sum_j A[i][j])^-1/2 ----------------
__global__ __launch_bounds__(256) void k_rownorm(const float* __restrict__ A,
                                                 float* __restrict__ norm) {
  const int row = blockIdx.x;
  const f32x4* ar = (const f32x4*)(A + (size_t)row * NN);
  float s = 0.f;
#pragma unroll 4
  for (int c = threadIdx.x; c < NN / 4; c += 256) {
    f32x4 v = __builtin_nontemporal_load(&ar[c]);
    s += (v.x + v.y) + (v.z + v.w);
  }
#pragma unroll
  for (int off = 32; off > 0; off >>= 1) s += __shfl_xor(s, off, 64);
  __shared__ float red[4];
  const int lane = threadIdx.x & 63, w = threadIdx.x >> 6;
  if (lane == 0) red[w] = s;
  __syncthreads();
  if (threadIdx.x == 0) {
    float d = (red[0] + red[1]) + (red[2] + red[3]);
    norm[row] = d > 0.f ? 1.f / sqrtf(d) : 0.f;
  }
}

// ------- kernel 2: Ht[o][j] = bf16( norm[j] * sum_f F[j][f]*W[o][f] ) -------
// 512 blocks x 256 thr; block = 32 j-rows, 4 waves each own 32 o-cols.
__global__ __launch_bounds__(256) void k_fwt(const float* __restrict__ F,
                                             const float* __restrict__ W,
                                             const float* __restrict__ norm,
                                             unsigned short* __restrict__ Ht) {
  const int tid = threadIdx.x;
  const int wv = tid >> 6;
  const int l = tid & 63;
  const int lr = l & 31, lg = l >> 5;
  const int j0 = blockIdx.x * 32;

  const float* fp = F + (size_t)(j0 + lr) * FD + lg * 8;
  const float* wp = W + (size_t)(wv * 32 + lr) * FD + lg * 8;

  f32x16 acc;
#pragma unroll
  for (int i = 0; i < 16; ++i) acc[i] = 0.f;

#pragma unroll
  for (int kf = 0; kf < 8; ++kf) {
    f32x4 fa = *(const f32x4*)(fp + kf * 16);
    f32x4 fb = *(const f32x4*)(fp + kf * 16 + 4);
    f32x4 wa = *(const f32x4*)(wp + kf * 16);
    f32x4 wb = *(const f32x4*)(wp + kf * 16 + 4);
    bf16x8 av = __builtin_bit_cast(bf16x8, pack8(fa, fb));
    bf16x8 bv = __builtin_bit_cast(bf16x8, pack8(wa, wb));
    acc = __builtin_amdgcn_mfma_f32_32x32x16_bf16(av, bv, acc, 0, 0, 0);
  }

  const int o = wv * 32 + lr;
  unsigned short* hrow = Ht + (size_t)o * NN;
#pragma unroll
  for (int g = 0; g < 4; ++g) {
    const int jb = j0 + g * 8 + lg * 4;  // D row = (reg&3) + 8*(reg>>2) + 4*lg
    u16x4 q;
#pragma unroll
    for (int r2 = 0; r2 < 4; ++r2) q[r2] = f2bf(acc[g * 4 + r2] * norm[jb + r2]);
    *(u16x4*)(hrow + jb) = q;
  }
}

// ---------- kernel 3: out[i][o] = norm[i] * sum_j A[i][j]*Ht[o][j] + b[o] ----------
// BM=32, BN=128, BK=128. 512 blocks x 256 thr (4 waves), 2 blocks/CU (80KB LDS).
// A: global f32 -> regs (nontemporal) -> cvt bf16 -> swizzled LDS.
// B: global bf16 (Ht, L2-resident) -> LDS via global_load_lds, pre-swizzled source.
// Swizzle: byte ^= (row&7)<<4  -> conflict-free ds_read_b128.
__global__ __launch_bounds__(256, 2) void k_gcn_gemm(
    const float* __restrict__ A, const unsigned short* __restrict__ Ht,
    const float* __restrict__ norm, const float* __restrict__ bias,
    float* __restrict__ out) {
  __shared__ __align__(16) unsigned short Alds[2][32 * 128];
  __shared__ __align__(16) unsigned short Blds[2][128 * 128];

  const int tid = threadIdx.x;
  const int i0 = blockIdx.x * 32;

  // A staging: thread -> (row = tid>>3, 16 k-elements at (tid&7)*16)
  const int arow = tid >> 3;
  const int akseg = (tid & 7) << 4;
  const float* aptr = A + (size_t)(i0 + arow) * NN + akseg;
  const unsigned abyte =
      (unsigned)(arow * 256 + akseg * 2) ^ (unsigned)((arow & 7) << 4);

  // B staging: chunk i: col = i*16 + (tid>>4); LDS linear = i*4096 + tid*16;
  // source pre-swizzled so swizzled reads land on true (col,k).
  const unsigned bsoff =
      (unsigned)((tid & 15) * 16) ^ (unsigned)(((tid >> 4) & 7) << 4);
  const char* bsrc = (const char*)Ht + (size_t)(tid >> 4) * (NN * 2) + bsoff;

  // fragment addressing
  const int wv = tid >> 6;
  const int l = tid & 63;
  const int lr = l & 31, lg = l >> 5;
  const unsigned swz = (unsigned)((lr & 7) << 4);
  const unsigned lg16 = (unsigned)(lg * 16);
  const unsigned arb = (unsigned)(lr * 256);
  const unsigned brb = (unsigned)((wv * 32 + lr) * 256);

  f32x16 acc;
#pragma unroll
  for (int i = 0; i < 16; ++i) acc[i] = 0.f;

#define STAGE_B(T, NXT)                                                     \
  {                                                                         \
    const char* bs_ = bsrc + (size_t)(T) * 256;                             \
    char* bl_ = (char*)Blds[NXT] + (size_t)tid * 16;                        \
    _Pragma("unroll") for (int i_ = 0; i_ < 8; ++i_)                        \
        gload_lds16(bs_ + (size_t)i_ * (16 * NN * 2), bl_ + i_ * 4096);     \
  }

  // prologue: stage tile 0 into buffer 0
  STAGE_B(0, 0)
  {
    f32x4 r0 = __builtin_nontemporal_load((const f32x4*)(aptr));
    f32x4 r1 = __builtin_nontemporal_load((const f32x4*)(aptr + 4));
    f32x4 r2 = __builtin_nontemporal_load((const f32x4*)(aptr + 8));
    f32x4 r3 = __builtin_nontemporal_load((const f32x4*)(aptr + 12));
    *(u16x8*)((char*)Alds[0] + abyte) = pack8(r0, r1);
    *(u16x8*)((char*)Alds[0] + (abyte ^ 16u)) = pack8(r2, r3);
  }
  __syncthreads();

#define GSTEP(CUR, NXT, T)                                                  \
  {                                                                         \
    const int t_ = (T);                                                     \
    const bool pf_ = (t_ + 1) < 128;                                        \
    f32x4 r0 = {}, r1 = {}, r2 = {}, r3 = {};                               \
    if (pf_) {                                                              \
      STAGE_B(t_ + 1, NXT)                                                  \
      const float* ap_ = aptr + (size_t)(t_ + 1) * 128;                     \
      r0 = __builtin_nontemporal_load((const f32x4*)(ap_));                 \
      r1 = __builtin_nontemporal_load((const f32x4*)(ap_ + 4));             \
      r2 = __builtin_nontemporal_load((const f32x4*)(ap_ + 8));             \
      r3 = __builtin_nontemporal_load((const f32x4*)(ap_ + 12));            \
    }                                                                       \
    _Pragma("unroll") for (int kf = 0; kf < 8; ++kf) {                      \
      unsigned ko = ((unsigned)(kf * 32) + lg16) ^ swz;                     \
      u16x8 av = *(const u16x8*)((const char*)Alds[CUR] + (arb + ko));      \
      u16x8 bv = *(const u16x8*)((const char*)Blds[CUR] + (brb + ko));      \
      acc = __builtin_amdgcn_mfma_f32_32x32x16_bf16(                        \
          __builtin_bit_cast(bf16x8, av), __builtin_bit_cast(bf16x8, bv),   \
          acc, 0, 0, 0);                                                    \
    }                                                                       \
    if (pf_) {                                                              \
      *(u16x8*)((char*)Alds[NXT] + abyte) = pack8(r0, r1);                  \
      *(u16x8*)((char*)Alds[NXT] + (abyte ^ 16u)) = pack8(r2, r3);          \
    }                                                                       \
    __syncthreads();                                                        \
  }

#pragma unroll 1
  for (int t = 0; t < 128; t += 2) {
    GSTEP(0, 1, t)
    GSTEP(1, 0, t + 1)
  }

  // epilogue: D col = lane&31 (+32*wave), row = (reg&3)+8*(reg>>2)+4*(lane>>5)
  const int col = wv * 32 + lr;
  const float bb = bias[col];
#pragma unroll
  for (int g = 0; g < 4; ++g) {
    const int jb = g * 8 + lg * 4;
#pragma unroll
    for (int r2 = 0; r2 < 4; ++r2) {
      const int row = i0 + jb + r2;
      out[(size_t)row * FD + col] = norm[row] * acc[g * 4 + r2] + bb;
    }
  }
#undef GSTEP
#undef STAGE_B
}

extern "C" void kernel_launch(void* const* d_in, const int* in_sizes, int n_in,
                              void* d_out, int out_size, void* d_ws,
                              size_t ws_size, hipStream_t stream) {
  (void)in_sizes; (void)n_in; (void)out_size; (void)ws_size;
  const float* A = (const float*)d_in[0];
  const float* F = (const float*)d_in[1];
  const float* W = (const float*)d_in[2];
  const float* b = (const float*)d_in[3];
  float* out = (float*)d_out;

  float* norm = (float*)d_ws;                                  // 64 KB
  unsigned short* Ht = (unsigned short*)((char*)d_ws + 65536); // 4 MB, bf16 [128][16384]

  k_rownorm<<<NN, 256, 0, stream>>>(A, norm);
  k_fwt<<<NN / 32, 256, 0, stream>>>(F, W, norm, Ht);
  k_gcn_gemm<<<NN / 32, 256, 0, stream>>>(A, Ht, norm, b, out);
}

// Round 2
// 507.907 us; speedup vs baseline: 1.0332x; 1.0332x over previous
//
#include <hip/hip_runtime.h>
#include <stdint.h>

#define NN 16384
#define FD 128

typedef float f32x4 __attribute__((ext_vector_type(4)));
typedef float f32x16 __attribute__((ext_vector_type(16)));
typedef __bf16 bf16x8 __attribute__((ext_vector_type(8)));
typedef unsigned short u16x8 __attribute__((ext_vector_type(8)));
typedef unsigned short u16x4 __attribute__((ext_vector_type(4)));

static __device__ __forceinline__ unsigned short f2bf(float x) {
  return __builtin_bit_cast(unsigned short, (__bf16)x);
}

static __device__ __forceinline__ u16x8 pack8(f32x4 a, f32x4 b) {
  u16x8 r;
  r[0] = f2bf(a.x); r[1] = f2bf(a.y); r[2] = f2bf(a.z); r[3] = f2bf(a.w);
  r[4] = f2bf(b.x); r[5] = f2bf(b.y); r[6] = f2bf(b.z); r[7] = f2bf(b.w);
  return r;
}

// ---------------- kernel 1: norm[i] = (sum_j A[i][j])^-1/2 ----------------
__global__ __launch_bounds__(256) void k_rownorm(const float* __restrict__ A,
                                                 float* __restrict__ norm) {
  const int row = blockIdx.x;
  const f32x4* ar = (const f32x4*)(A + (size_t)row * NN);
  float s = 0.f;
#pragma unroll 4
  for (int c = threadIdx.x; c < NN / 4; c += 256) {
    f32x4 v = __builtin_nontemporal_load(&ar[c]);
    s += (v.x + v.y) + (v.z + v.w);
  }
#pragma unroll
  for (int off = 32; off > 0; off >>= 1) s += __shfl_xor(s, off, 64);
  __shared__ float red[4];
  const int lane = threadIdx.x & 63, w = threadIdx.x >> 6;
  if (lane == 0) red[w] = s;
  __syncthreads();
  if (threadIdx.x == 0) {
    float d = (red[0] + red[1]) + (red[2] + red[3]);
    norm[row] = d > 0.f ? 1.f / sqrtf(d) : 0.f;
  }
}

// ------- kernel 2: Bfrag = fragment-major bf16( norm[j] * (F @ W^T)[j][o] ) -------
// Bfrag layout: entry (t = j>>4, c = o>>5, lane l, e) at byte ((t*4+c)*64 + l)*16 + e*2
// holds norm[j]*H[j][o] with o = c*32 + (l&31), j = t*16 + (l>>5)*8 + e.
// This is exactly the mfma_32x32x16 B-operand fragment for k-tile t, col-group c.
__global__ __launch_bounds__(256) void k_fwt(const float* __restrict__ F,
                                             const float* __restrict__ W,
                                             const float* __restrict__ norm,
                                             unsigned short* __restrict__ Bfrag) {
  const int tid = threadIdx.x;
  const int wv = tid >> 6;
  const int l = tid & 63;
  const int lr = l & 31, lg = l >> 5;
  const int j0 = blockIdx.x * 32;

  const float* fp = F + (size_t)(j0 + lr) * FD + lg * 8;
  const float* wp = W + (size_t)(wv * 32 + lr) * FD + lg * 8;

  f32x16 acc;
#pragma unroll
  for (int i = 0; i < 16; ++i) acc[i] = 0.f;

#pragma unroll
  for (int kf = 0; kf < 8; ++kf) {
    f32x4 fa = *(const f32x4*)(fp + kf * 16);
    f32x4 fb = *(const f32x4*)(fp + kf * 16 + 4);
    f32x4 wa = *(const f32x4*)(wp + kf * 16);
    f32x4 wb = *(const f32x4*)(wp + kf * 16 + 4);
    bf16x8 av = __builtin_bit_cast(bf16x8, pack8(fa, fb));
    bf16x8 bv = __builtin_bit_cast(bf16x8, pack8(wa, wb));
    acc = __builtin_amdgcn_mfma_f32_32x32x16_bf16(av, bv, acc, 0, 0, 0);
  }

  // D: col(o-local) = lr, row(j-local) = (reg&3) + 8*(reg>>2) + 4*lg
  const int jt = blockIdx.x * 2;  // j0 >> 4
#pragma unroll
  for (int g = 0; g < 4; ++g) {
    const int jb = j0 + g * 8 + lg * 4;
    u16x4 q;
#pragma unroll
    for (int r2 = 0; r2 < 4; ++r2) q[r2] = f2bf(acc[g * 4 + r2] * norm[jb + r2]);
    const size_t byteoff =
        ((size_t)((jt + (g >> 1)) * 4 + wv) * 64 + (g & 1) * 32 + lr) * 16 +
        lg * 8;
    *(u16x4*)((char*)Bfrag + byteoff) = q;
  }
}

// ---------- kernel 3: out[i][o] = norm[i] * sum_j A[i][j]*(norm[j]*H[j][o]) + b[o] ----------
// BM=32, BK=256. 512 blocks x 512 thr (8 waves = 4 col-groups x 2 k-groups).
// A: global f32 (nontemporal) -> regs -> bf16 -> swizzled LDS (2 x 16 KB dbuf).
// B: fragment-major bf16 from L2, coalesced 1KB/wave global_load_dwordx4 -> regs. No B LDS.
// K-split (kg=0/1) reduced through LDS in epilogue; coalesced f32x4 out stores.
__global__ __launch_bounds__(512, 4) void k_gcn_gemm(
    const float* __restrict__ A, const unsigned short* __restrict__ Bfrag,
    const float* __restrict__ norm, const float* __restrict__ bias,
    float* __restrict__ out) {
  __shared__ __align__(16) unsigned short Alds[2][32 * 256];  // 2 x 16 KB

  const int tid = threadIdx.x;
  const int i0 = blockIdx.x * 32;

  // A staging: thread -> (row = tid>>4, 16 k-elements at (tid&15)*16)
  const int arow = tid >> 4;
  const int akseg = (tid & 15) << 4;
  const float* aptr = A + (size_t)(i0 + arow) * NN + akseg;
  const unsigned abyte =
      (unsigned)(arow * 512 + akseg * 2) ^ (unsigned)((arow & 7) << 4);

  // fragment addressing
  const int wv = tid >> 6;
  const int c = wv & 3, kg = wv >> 2;
  const int l = tid & 63;
  const int lr = l & 31, lg = l >> 5;
  const unsigned swz = (unsigned)((lr & 7) << 4);
  const unsigned arb = (unsigned)(lr * 512);
  const unsigned kgb = (unsigned)(kg * 256);  // kg*128 elements in bytes

  // B: lane base byte = ((c*64) + l)*16; per k-tile t add t*4*64*16 = t*4096
  const char* bptr = (const char*)Bfrag + (size_t)(c * 64 + l) * 16 +
                     (size_t)kg * 8 * 4096;

  f32x16 acc;
#pragma unroll
  for (int i = 0; i < 16; ++i) acc[i] = 0.f;

  // prologue: stage tile 0 into buffer 0
  {
    f32x4 r0 = __builtin_nontemporal_load((const f32x4*)(aptr));
    f32x4 r1 = __builtin_nontemporal_load((const f32x4*)(aptr + 4));
    f32x4 r2 = __builtin_nontemporal_load((const f32x4*)(aptr + 8));
    f32x4 r3 = __builtin_nontemporal_load((const f32x4*)(aptr + 12));
    *(u16x8*)((char*)Alds[0] + abyte) = pack8(r0, r1);
    *(u16x8*)((char*)Alds[0] + (abyte ^ 16u)) = pack8(r2, r3);
  }
  __syncthreads();

#define GSTEP(CUR, NXT, S)                                                  \
  {                                                                         \
    const int s_ = (S);                                                     \
    const bool pf_ = (s_ + 1) < 64;                                         \
    f32x4 r0 = {}, r1 = {}, r2 = {}, r3 = {};                               \
    if (pf_) {                                                              \
      const float* ap_ = aptr + (size_t)(s_ + 1) * 256;                     \
      r0 = __builtin_nontemporal_load((const f32x4*)(ap_));                 \
      r1 = __builtin_nontemporal_load((const f32x4*)(ap_ + 4));             \
      r2 = __builtin_nontemporal_load((const f32x4*)(ap_ + 8));             \
      r3 = __builtin_nontemporal_load((const f32x4*)(ap_ + 12));            \
    }                                                                       \
    const char* bp_ = bptr + (size_t)s_ * (16 * 4096);                      \
    _Pragma("unroll") for (int kf = 0; kf < 8; ++kf) {                      \
      u16x8 bv = *(const u16x8*)(bp_ + (size_t)kf * 4096);                  \
      unsigned ko = (kgb + (unsigned)(kf * 32) + (unsigned)(lg * 16)) ^ swz;\
      u16x8 av = *(const u16x8*)((const char*)Alds[CUR] + (arb + ko));      \
      acc = __builtin_amdgcn_mfma_f32_32x32x16_bf16(                        \
          __builtin_bit_cast(bf16x8, av), __builtin_bit_cast(bf16x8, bv),   \
          acc, 0, 0, 0);                                                    \
    }                                                                       \
    if (pf_) {                                                              \
      *(u16x8*)((char*)Alds[NXT] + abyte) = pack8(r0, r1);                  \
      *(u16x8*)((char*)Alds[NXT] + (abyte ^ 16u)) = pack8(r2, r3);          \
    }                                                                       \
    __syncthreads();                                                        \
  }

#pragma unroll 1
  for (int s = 0; s < 64; s += 2) {
    GSTEP(0, 1, s)
    GSTEP(1, 0, s + 1)
  }
#undef GSTEP

  // ---- epilogue: reduce kg halves via LDS, then coalesced store ----
  // D: col(o-local) = c*32 + lr, row(i-local) = g*8 + lg*4 + r2
  float* red = (float*)Alds;  // 32x128 f32 = 16 KB (loop's final barrier passed)
  if (kg == 1) {
#pragma unroll
    for (int g = 0; g < 4; ++g) {
      const int jb = g * 8 + lg * 4;
#pragma unroll
      for (int r2 = 0; r2 < 4; ++r2)
        red[(jb + r2) * 128 + c * 32 + lr] = acc[g * 4 + r2];
    }
  }
  __syncthreads();
  if (kg == 0) {
#pragma unroll
    for (int g = 0; g < 4; ++g) {
      const int jb = g * 8 + lg * 4;
#pragma unroll
      for (int r2 = 0; r2 < 4; ++r2)
        red[(jb + r2) * 128 + c * 32 + lr] += acc[g * 4 + r2];
    }
  }
  __syncthreads();

  {
    const int row = tid >> 4;            // 0..31
    const int colseg = (tid & 15) * 8;   // 0..120
    const float nm = norm[i0 + row];
    f32x4 v0 = *(const f32x4*)(red + row * 128 + colseg);
    f32x4 v1 = *(const f32x4*)(red + row * 128 + colseg + 4);
    f32x4 b0 = *(const f32x4*)(bias + colseg);
    f32x4 b1 = *(const f32x4*)(bias + colseg + 4);
    f32x4 o0, o1;
    o0.x = nm * v0.x + b0.x; o0.y = nm * v0.y + b0.y;
    o0.z = nm * v0.z + b0.z; o0.w = nm * v0.w + b0.w;
    o1.x = nm * v1.x + b1.x; o1.y = nm * v1.y + b1.y;
    o1.z = nm * v1.z + b1.z; o1.w = nm * v1.w + b1.w;
    float* op = out + (size_t)(i0 + row) * FD + colseg;
    *(f32x4*)op = o0;
    *(f32x4*)(op + 4) = o1;
  }
}

extern "C" void kernel_launch(void* const* d_in, const int* in_sizes, int n_in,
                              void* d_out, int out_size, void* d_ws,
                              size_t ws_size, hipStream_t stream) {
  (void)in_sizes; (void)n_in; (void)out_size; (void)ws_size;
  const float* A = (const float*)d_in[0];
  const float* F = (const float*)d_in[1];
  const float* W = (const float*)d_in[2];
  const float* b = (const float*)d_in[3];
  float* out = (float*)d_out;

  float* norm = (float*)d_ws;                                     // 64 KB
  unsigned short* Bfrag = (unsigned short*)((char*)d_ws + 65536); // 4 MB

  k_rownorm<<<NN, 256, 0, stream>>>(A, norm);
  k_fwt<<<NN / 32, 256, 0, stream>>>(F, W, norm, Bfrag);
  k_gcn_gemm<<<NN / 32, 512, 0, stream>>>(A, Bfrag, norm, b, out);
}